// Round 11
// baseline (2247.537 us; speedup 1.0000x reference)
//
#include <hip/hip_runtime.h>

#define T_DIM 512
#define N_DIM 1024
#define K_DIM 2048

typedef _Float16 f16;
typedef _Float16 f16x8 __attribute__((ext_vector_type(8)));
typedef float f32x16 __attribute__((ext_vector_type(16)));
typedef __attribute__((address_space(1))) const unsigned int GU32;
typedef __attribute__((address_space(3))) unsigned int LU32;

__device__ __forceinline__ void gload16(const void* g, void* l) {
  __builtin_amdgcn_global_load_lds((GU32*)g, (LU32*)l, 16, 0, 0);
}

// ---------------------------------------------------------------------------
// Kernel 0: pre-split w into f16 {w0,w1} as the gemm's BK=32 A-LDS image.
// wimg[nt(8)][it(64)][slot(8)=(c*4+kc*2+lhi)][row(128)][8]  (16 KB per tile)
//   v = 64*w ; w0 = f16(v) ; w1 = f16((v - w0) * 4096)
// ---------------------------------------------------------------------------
__global__ __launch_bounds__(256) void presplit_w(const float* __restrict__ w,
                                                  f16* __restrict__ wimg) {
  const int gid = blockIdx.x * 256 + threadIdx.x;  // 262144 = 1024 n x 256 ko
  const int ko = gid >> 10;   // k-octet 0..255
  const int n = gid & 1023;
  const float* src = w + (size_t)n * K_DIM + (ko << 3);
  const float4 v0 = *(const float4*)src;
  const float4 v1 = *(const float4*)(src + 4);
  const float vv[8] = {v0.x, v0.y, v0.z, v0.w, v1.x, v1.y, v1.z, v1.w};
  f16x8 h0, h1;
#pragma unroll
  for (int q = 0; q < 8; ++q) {
    const float v = vv[q] * 64.f;
    const f16 a = (f16)v;
    h0[q] = a;
    h1[q] = (f16)((v - (float)a) * 4096.f);
  }
  const int nt = n >> 7, row = n & 127;
  const int it = ko >> 2;          // k32 tile
  const int o = ko & 3;            // octet in tile
  const int kc = o >> 1, lhi = o & 1;
  f16* blk = wimg + (size_t)(nt * 64 + it) * 8192;
  *(f16x8*)&blk[((kc * 2 + lhi) * 128 + row) * 8] = h0;        // comp 0
  *(f16x8*)&blk[((4 + kc * 2 + lhi) * 128 + row) * 8] = h1;    // comp 1
}

// ---------------------------------------------------------------------------
// Kernel 1: z[b][t][n] = sum_i w[n][i]*x[b][i][t]  (z into d_out, [B][T][N])
// R2-proven register shell: 512 thr, 8 waves (2n x 4t), wave tile 64x64 (2,2),
// BK=32, NO occupancy attrs (R2 measured: VGPR=104, acc->AGPR, zero spill;
// every waves_per_eu/min-wg variant R3-R10 spilled 0.8-4.6 GB).
// Upgrades vs R2: A via global_load_lds from wimg (no A-split VALU),
// x staged with all-16B slot-layout writes (R10: 0 bank conflicts),
// XCD swizzle: 8 nt-siblings of an x-panel on one XCD (R10: FETCH 390MB).
// acc0 += w0*x0 ; acc1 += w0*x1 + w1*x0 ; z = acc0/64 + acc1/(64*4096).
// ---------------------------------------------------------------------------
__global__ __launch_bounds__(512)
void gemm_split(const float* __restrict__ x,
                const f16* __restrict__ wimg,
                float* __restrict__ z) {
  // p -> (XCD slot c, nt, Ghi); G = (Ghi<<3)|c -> (b, tt)
  const int p = blockIdx.x;       // 0..1023
  const int c = p & 7;
  const int r = p >> 3;
  const int nt = r & 7;
  const int G = ((r >> 3) << 3) | c;  // 0..127
  const int b = G >> 1;
  const int tt = G & 1;
  const int n0 = nt << 7, t0 = tt << 8;

  __shared__ f16 sA[2][8192];   // [slot(8)][row(128)][8]  16 KB/buf
  __shared__ f16 sB[2][16384];  // [slot(8)][t(256)][8]    32 KB/buf

  const int tid = threadIdx.x;
  const int lane = tid & 63;
  const int l31 = lane & 31, lhi = lane >> 5;
  const int wv = tid >> 6;   // 0..7
  const int wm = wv >> 2;    // 0..1 (n)
  const int wt = wv & 3;     // 0..3 (t)

  // x staging: tcol 0..255, kh16 0..1 (16 k each)
  const int tcol = tid & 255, kh16 = tid >> 8;
  const float* pX = x + (size_t)b * (K_DIM * T_DIM) + (size_t)(kh16 * 16) * T_DIM + t0 + tcol;

  const f16* wbase = wimg + (size_t)nt * (64 * 8192);
  const int dmaoff = tid * 8;  // 2 chunks of 16B per thread

  // fragment read offsets (f16 elems): slot = c*4 + kc*2 + lhi
  const int aO = (lhi * 128 + wm * 64 + l31) * 8;   // + (c*4+kc*2)*1024 + f*256
  const int bO = (lhi * 256 + wt * 64 + l31) * 8;   // + (c*4+kc*2)*2048 + g*256

  // x staging write offsets: slot(c, lh) = c*4 + kh16*2 + lh
  const int xoB = kh16 * 2 * 256 * 8 + tcol * 8;    // + c*4*2048 + lh*2048

  f32x16 acc0[2][2], acc1[2][2];
#pragma unroll
  for (int i = 0; i < 2; ++i)
#pragma unroll
    for (int j = 0; j < 2; ++j)
#pragma unroll
      for (int q = 0; q < 16; ++q) {
        acc0[i][j][q] = 0.f;
        acc1[i][j][q] = 0.f;
      }

  float vb[16];

#define LOADVB(IT)                                                      \
  {                                                                     \
    const float* px = pX + (size_t)((IT) * 32) * T_DIM;                 \
    _Pragma("unroll")                                                   \
    for (int jj = 0; jj < 16; ++jj) vb[jj] = px[(size_t)jj * T_DIM];    \
  }

#define STAGE(BUF, IT)                                                  \
  {                                                                     \
    const f16* ws = wbase + (size_t)(IT) * 8192;                        \
    gload16(ws + dmaoff, &sA[BUF][dmaoff]);                             \
    gload16(ws + dmaoff + 4096, &sA[BUF][dmaoff + 4096]);               \
    f16x8 h0a, h0b, h1a, h1b;                                           \
    _Pragma("unroll")                                                   \
    for (int q = 0; q < 8; ++q) {                                       \
      float v = vb[q];                                                  \
      f16 a = (f16)v;                                                   \
      h0a[q] = a;                                                       \
      h1a[q] = (f16)((v - (float)a) * 4096.f);                          \
      v = vb[8 + q];                                                    \
      a = (f16)v;                                                       \
      h0b[q] = a;                                                       \
      h1b[q] = (f16)((v - (float)a) * 4096.f);                          \
    }                                                                   \
    *(f16x8*)&sB[BUF][xoB] = h0a;                                       \
    *(f16x8*)&sB[BUF][xoB + 2048] = h0b;                                \
    *(f16x8*)&sB[BUF][xoB + 8192] = h1a;                                \
    *(f16x8*)&sB[BUF][xoB + 8192 + 2048] = h1b;                         \
  }

#define COMPUTE(BUF)                                                    \
  {                                                                     \
    _Pragma("unroll")                                                   \
    for (int kc = 0; kc < 2; ++kc) {                                    \
      f16x8 a0[2], a1[2], b0[2], b1[2];                                 \
      _Pragma("unroll")                                                 \
      for (int f = 0; f < 2; ++f) {                                     \
        a0[f] = *(const f16x8*)&sA[BUF][aO + kc * 2048 + f * 256];      \
        a1[f] = *(const f16x8*)&sA[BUF][aO + kc * 2048 + f * 256 + 4096]; \
      }                                                                 \
      _Pragma("unroll")                                                 \
      for (int g = 0; g < 2; ++g) {                                     \
        b0[g] = *(const f16x8*)&sB[BUF][bO + kc * 4096 + g * 256];      \
        b1[g] = *(const f16x8*)&sB[BUF][bO + kc * 4096 + g * 256 + 8192]; \
      }                                                                 \
      _Pragma("unroll")                                                 \
      for (int f = 0; f < 2; ++f)                                       \
        _Pragma("unroll")                                               \
        for (int g = 0; g < 2; ++g) {                                   \
          acc0[f][g] = __builtin_amdgcn_mfma_f32_32x32x16_f16(a0[f], b0[g], acc0[f][g], 0, 0, 0); \
          acc1[f][g] = __builtin_amdgcn_mfma_f32_32x32x16_f16(a0[f], b1[g], acc1[f][g], 0, 0, 0); \
          acc1[f][g] = __builtin_amdgcn_mfma_f32_32x32x16_f16(a1[f], b0[g], acc1[f][g], 0, 0, 0); \
        }                                                               \
    }                                                                   \
  }

  // prologue (R2 ordering)
  LOADVB(0);
  STAGE(0, 0);
  LOADVB(1);
  __syncthreads();

  int cur = 0;
  for (int it = 0; it < 64; ++it) {
    if (it < 63) STAGE(cur ^ 1, it + 1);
    if (it < 62) LOADVB(it + 2);
    if (cur == 0) {
      COMPUTE(0);
    } else {
      COMPUTE(1);
    }
    __syncthreads();
    cur ^= 1;
  }

#undef LOADVB
#undef STAGE
#undef COMPUTE

  // epilogue: z = acc0/64 + acc1/(64*4096), stored z[t][n]
  float* zb = z + (size_t)b * T_DIM * N_DIM;
  const float C0 = 0.015625f;
  const float C1 = 3.814697265625e-06f;
#pragma unroll
  for (int f = 0; f < 2; ++f)
#pragma unroll
    for (int g = 0; g < 2; ++g) {
      const int t = t0 + wt * 64 + g * 32 + l31;
      float* orow = zb + (size_t)t * N_DIM + n0 + wm * 64 + f * 32 + lhi * 4;
#pragma unroll
      for (int q = 0; q < 4; ++q) {
        float4 o;
        o.x = acc0[f][g][4 * q + 0] * C0 + acc1[f][g][4 * q + 0] * C1;
        o.y = acc0[f][g][4 * q + 1] * C0 + acc1[f][g][4 * q + 1] * C1;
        o.z = acc0[f][g][4 * q + 2] * C0 + acc1[f][g][4 * q + 2] * C1;
        o.w = acc0[f][g][4 * q + 3] * C0 + acc1[f][g][4 * q + 3] * C1;
        *(float4*)(orow + q * 8) = o;
      }
    }
}

// ---------------------------------------------------------------------------
// Kernel 2: sequential CUBA-KWTA recurrence, ballot-based spike count.
// ---------------------------------------------------------------------------
__global__ __launch_bounds__(256) void kwta_scan(const float* __restrict__ z,
                                                 const float* __restrict__ se,
                                                 unsigned int* __restrict__ bits) {
  const int b = blockIdx.x;
  const int tid = threadIdx.x;
  const int lane = tid & 63;
  const int wid = tid >> 6;

  float a = se[0];
  a = fminf(fmaxf(a, 0.f), 1.f);
  const float ap1 = 1.f + a;
  const float RB = 0.8046875f;  // TH*(N-2K)/N/WS exact

  __shared__ float part[2][4];

  const float* zb = z + (size_t)b * T_DIM * N_DIM + tid * 4;
  unsigned int* gb = bits + (size_t)b * 16 * N_DIM + tid * 4;

  float4 r0 = *(const float4*)(zb);
  float4 r1 = *(const float4*)(zb + 1 * N_DIM);
  float4 r2 = *(const float4*)(zb + 2 * N_DIM);
  float4 r3 = *(const float4*)(zb + 3 * N_DIM);
  float4 r4 = *(const float4*)(zb + 4 * N_DIM);
  float4 r5 = *(const float4*)(zb + 5 * N_DIM);
  float4 r6 = *(const float4*)(zb + 6 * N_DIM);
  float4 r7 = *(const float4*)(zb + 7 * N_DIM);

  float u0 = 0.f, u1 = 0.f, u2 = 0.f, u3 = 0.f;
  float v0 = 0.f, v1 = 0.f, v2 = 0.f, v3 = 0.f;
  float s0 = 0.f, s1 = 0.f, s2 = 0.f, s3 = 0.f;
  float S = 0.f;
  unsigned int c0 = 0, c1 = 0, c2 = 0, c3 = 0;

#define NEU(U, V, SV, C, ZV)                            \
  {                                                     \
    const float fb  = fmaf(ap1, SV, -S) + RB;           \
    const float inp = ZV + fb;                          \
    U = fmaf(0.75f, U, inp);                            \
    V = fmaf(0.9f, V, U);                               \
    const bool sp = (V >= 1.0f);                        \
    SV = sp ? 1.0f : 0.0f;                              \
    V  = sp ? 0.0f : V;                                 \
    C |= ((unsigned int)sp) << (t & 31);                \
    msum += __popcll(__ballot(sp));                     \
  }

#define STEP(KK, RQ)                                                    \
  {                                                                     \
    const int t = tbase + KK;                                           \
    const float4 z4 = RQ;                                               \
    int tn = t + 8;                                                     \
    if (tn > 511) tn = 511;                                             \
    RQ = *(const float4*)(zb + (size_t)tn * N_DIM);                     \
    int msum = 0;                                                       \
    NEU(u0, v0, s0, c0, z4.x)                                           \
    NEU(u1, v1, s1, c1, z4.y)                                           \
    NEU(u2, v2, s2, c2, z4.z)                                           \
    NEU(u3, v3, s3, c3, z4.w)                                           \
    if (lane == 0) part[t & 1][wid] = (float)msum;                      \
    __syncthreads();                                                    \
    S = (part[t & 1][0] + part[t & 1][1]) +                             \
        (part[t & 1][2] + part[t & 1][3]);                              \
    if ((t & 31) == 31) {                                               \
      *(uint4*)(gb + (size_t)(t >> 5) * N_DIM) =                        \
          make_uint4(c0, c1, c2, c3);                                   \
      c0 = c1 = c2 = c3 = 0;                                            \
    }                                                                   \
  }

  for (int tbase = 0; tbase < T_DIM; tbase += 8) {
    STEP(0, r0)
    STEP(1, r1)
    STEP(2, r2)
    STEP(3, r3)
    STEP(4, r4)
    STEP(5, r5)
    STEP(6, r6)
    STEP(7, r7)
  }
#undef STEP
#undef NEU
}

// ---------------------------------------------------------------------------
// Kernel 3: expand bits -> out[b][n][t] fp32 with 1-step delay shift.
// ---------------------------------------------------------------------------
__global__ __launch_bounds__(256) void expand_out(const unsigned int* __restrict__ bits,
                                                  float* __restrict__ out) {
  const int gid = blockIdx.x * 256 + threadIdx.x;
  const int l = gid & 63;
  const int row = gid >> 6;
  const int b = row >> 10;
  const int n = row & 1023;
  const unsigned int* r = bits + (size_t)b * 16 * N_DIM + n;

  unsigned int byte;
  if (l == 0) {
    byte = (r[0] << 1) & 0xFFu;
  } else {
    const int src = 8 * l - 1;
    const int w0 = src >> 5;
    const unsigned int lo = r[(size_t)w0 * N_DIM];
    const unsigned int hi = (w0 < 15) ? r[(size_t)(w0 + 1) * N_DIM] : 0u;
    const unsigned long long comb = ((unsigned long long)hi << 32) | (unsigned long long)lo;
    byte = (unsigned int)(comb >> (src & 31)) & 0xFFu;
  }

  float f[8];
#pragma unroll
  for (int k = 0; k < 8; ++k) f[k] = (float)((byte >> k) & 1u);

  float* o = out + ((size_t)row << 9) + (l << 3);
  *reinterpret_cast<float4*>(o)     = make_float4(f[0], f[1], f[2], f[3]);
  *reinterpret_cast<float4*>(o + 4) = make_float4(f[4], f[5], f[6], f[7]);
}

// ---------------------------------------------------------------------------
extern "C" void kernel_launch(void* const* d_in, const int* in_sizes, int n_in,
                              void* d_out, int out_size, void* d_ws, size_t ws_size,
                              hipStream_t stream) {
  const float* x  = (const float*)d_in[0];   // [64][2048][512]
  const float* w  = (const float*)d_in[1];   // [1024][2048]
  const float* se = (const float*)d_in[2];   // [1]
  float* out = (float*)d_out;                // [64][1024][512] fp32

  // wimg occupies d_ws[0, 8MB); bits reuses d_ws[0, 4MB) AFTER gemm (wimg dead)
  f16* wimg = (f16*)d_ws;
  unsigned int* bits = (unsigned int*)d_ws;

  presplit_w<<<1024, 256, 0, stream>>>(w, wimg);
  gemm_split<<<1024, 512, 0, stream>>>(x, wimg, out);
  kwta_scan<<<64, 256, 0, stream>>>(out, se, bits);
  expand_out<<<16384, 256, 0, stream>>>(bits, out);
}